// Round 7
// baseline (590.398 us; speedup 1.0000x reference)
//
#include <hip/hip_runtime.h>
#include <hip/hip_cooperative_groups.h>
#include <math.h>

namespace cg = cooperative_groups;

// ---------------------------------------------------------------------------
// TwoSimplicialAttention, MI355X. Mask kills attention for s < 2016; only the
// last 32 rows/batch (64 rows) carry attention; everything else is LN(x).
//
// R7: ONE cooperative kernel (1024 blocks x 256 thr, 4/CU co-resident).
// P1 proj-partials(512 blk) || LN-bulk(512 blk) -> sync -> P2 reduce ->
// sync -> P3 attn -> sync -> P4 wo-partials -> sync -> P5 LN-window.
// Fallback to 5 separate kernels if cooperative launch unsupported.
// ---------------------------------------------------------------------------

#define NS 8
// ws layout (floats)
#define YPART_OFF 0          // 8 x 262144  (each 64x4096)
#define YFULL_OFF 2097152    // 262144: Q|K|Kp|V each 64x1024
#define ZOFF      2359296    // 65536
#define DPART_OFF 2424832    // 8 x 65536
// total 2949120 floats = 11.8 MB

#define YQ  0
#define YK  65536
#define YKP 131072
#define YV  196608

#define SMEM_FLOATS 8576     // 34.3 KB -> 4 blocks/CU

__device__ __forceinline__ int sw_idx(int row, int d) {
  // XOR-swizzle for 32x64 tiles read as float4 along d by row-groups
  return row * 64 + ((((d >> 2) + (row >> 2)) & 15) << 2) + (d & 3);
}

// ---- P1a: proj partial tile. pid 0..511 -> (z, col0, ks of 8x128k) --------
__device__ __forceinline__ void proj_tile(
    int pid, int tid, const float* __restrict__ x,
    const float* __restrict__ Wq, const float* __restrict__ Wk,
    const float* __restrict__ Wkp, const float* __restrict__ Wv,
    float* __restrict__ ws, float* xs) {
  const int z    = (pid & 63) >> 4;
  const int col0 = (pid & 15) * 64;
  const int ks   = pid >> 6;                 // 0..7
  const int k0   = ks * 128;
  const float* __restrict__ W =
      (z == 0) ? Wq : ((z == 1) ? Wk : ((z == 2) ? Wkp : Wv));

  #pragma unroll
  for (int i = 0; i < 8; i++) {              // stage x^T 64r x 128k
    int e = i * 256 + tid; int r = e >> 5, q = e & 31;
    int b = r >> 5, t = r & 31;
    float4 v = *(const float4*)(x + ((b * 2048 + 2016 + t) * 1024 + k0 + q * 4));
    xs[(q * 4 + 0) * 65 + r] = v.x;
    xs[(q * 4 + 1) * 65 + r] = v.y;
    xs[(q * 4 + 2) * 65 + r] = v.z;
    xs[(q * 4 + 3) * 65 + r] = v.w;
  }
  __syncthreads();

  const int wave = __builtin_amdgcn_readfirstlane(tid >> 6);
  const int lane = tid & 63;                 // = row
  const float* __restrict__ Wt = W + (size_t)k0 * 1024 + col0 + wave * 16;
  float acc[16];
  #pragma unroll
  for (int c = 0; c < 16; c++) acc[c] = 0.f;
  #pragma unroll 4
  for (int kk = 0; kk < 128; kk++) {
    float xv = xs[kk * 65 + lane];           // conflict-free vector read
    const float* __restrict__ wrow = Wt + kk * 1024;  // uniform -> s_load x16
    #pragma unroll
    for (int c = 0; c < 16; c++) acc[c] = fmaf(xv, wrow[c], acc[c]);
  }
  __syncthreads();
  #pragma unroll
  for (int c = 0; c < 16; c++) xs[lane * 65 + wave * 16 + c] = acc[c];
  __syncthreads();
  float* __restrict__ Yo = ws + YPART_OFF + (size_t)ks * 262144 + z * 65536 + col0;
  #pragma unroll
  for (int i = 0; i < 16; i++) {
    int r = wave * 16 + i;
    Yo[r * 1024 + lane] = xs[r * 65 + lane]; // coalesced store
  }
}

// ---- LN of one row (wave-wide). WIN adds the 8 delta partials -------------
template <bool WIN>
__device__ __forceinline__ void ln_row(
    int row, int drow, int lane,
    const float4* __restrict__ x4, const float4* __restrict__ dpart4,
    const float4* __restrict__ g4, const float4* __restrict__ b4,
    float4* __restrict__ out4) {
  float4 v[4];
  #pragma unroll
  for (int i = 0; i < 4; i++) v[i] = x4[row * 256 + i * 64 + lane];
  if (WIN) {
    #pragma unroll
    for (int i = 0; i < 4; i++) {
      #pragma unroll
      for (int sp = 0; sp < NS; sp++) {
        float4 d = dpart4[sp * 16384 + drow * 256 + i * 64 + lane];
        v[i].x += d.x; v[i].y += d.y; v[i].z += d.z; v[i].w += d.w;
      }
    }
  }
  float sum = 0.f, ss = 0.f;
  #pragma unroll
  for (int i = 0; i < 4; i++) {
    sum += v[i].x + v[i].y + v[i].z + v[i].w;
    ss  += v[i].x * v[i].x + v[i].y * v[i].y + v[i].z * v[i].z + v[i].w * v[i].w;
  }
  #pragma unroll
  for (int off = 1; off < 64; off <<= 1) {
    sum += __shfl_xor(sum, off);
    ss  += __shfl_xor(ss, off);
  }
  float mu   = sum * (1.f / 1024.f);
  float var  = ss * (1.f / 1024.f) - mu * mu;
  float rstd = rsqrtf(var + 1e-5f);
  #pragma unroll
  for (int i = 0; i < 4; i++) {
    float4 g = g4[i * 64 + lane];
    float4 be = b4[i * 64 + lane];
    float4 o;
    o.x = (v[i].x - mu) * rstd * g.x + be.x;
    o.y = (v[i].y - mu) * rstd * g.y + be.y;
    o.z = (v[i].z - mu) * rstd * g.z + be.z;
    o.w = (v[i].w - mu) * rstd * g.w + be.w;
    out4[row * 256 + i * 64 + lane] = o;
  }
}

// ---- P3: attention. bid 0..511 -> (b,h,sg); waves 0,1 own s = sg*2+wave ---
__device__ __forceinline__ void attn_block(
    int bid, int tid, const float* __restrict__ Yf, float* __restrict__ Z,
    float* smem) {
  float* Kn = smem;                  // 2048, swizzled
  float* Kp = smem + 2048;           // 2048, swizzled
  float* Vs = smem + 4096;           // 2048 (stride-64 col reads: 2-way, free)
  float* qs = smem + 6144;           // 128
  float* Pt = smem + 6272;           // 2 x 1152 ([k][j] pad 36)
  const int wave = tid >> 6, lane = tid & 63;
  const int b = bid >> 8, h = (bid >> 4) & 15, sg = bid & 15;

  #pragma unroll
  for (int i = 0; i < 8; i++) {      // stage K/Kp/V (2048 each)
    int e = i * 256 + tid; int row = e >> 6, d = e & 63;
    int src = (b * 32 + row) * 1024 + h * 64 + d;
    Kn[sw_idx(row, d)] = Yf[YK + src];
    Kp[sw_idx(row, d)] = Yf[YKP + src];
    Vs[row * 64 + d]   = Yf[YV + src];
  }
  __syncthreads();

  for (int rr = 0; rr < 8; rr++) {   // l2norm K,Kp rows: 4 waves x 8 rows
    int row = wave * 8 + rr;
    int a = sw_idx(row, lane);
    float kv = Kn[a]; float s2 = kv * kv;
    #pragma unroll
    for (int off = 1; off < 64; off <<= 1) s2 += __shfl_xor(s2, off);
    Kn[a] = kv * (1.f / (sqrtf(s2) + 1e-7f));
    float pv = Kp[a]; float p2 = pv * pv;
    #pragma unroll
    for (int off = 1; off < 64; off <<= 1) p2 += __shfl_xor(p2, off);
    Kp[a] = pv * (1.f / (sqrtf(p2) + 1e-7f));
  }

  const int m = sg * 2 + wave;       // valid for wave<2
  const int r = b * 32 + m;
  if (wave < 2) {                    // q-hat
    float q = Yf[YQ + r * 1024 + h * 64 + lane];
    float q2 = q * q;
    #pragma unroll
    for (int off = 1; off < 64; off <<= 1) q2 += __shfl_xor(q2, off);
    qs[wave * 64 + lane] = q * (1.f / (sqrtf(q2) + 1e-7f));
  }
  __syncthreads();                   // norm + qs visible

  if (wave >= 2) return;             // no more block-level syncs below

  const int lj = lane >> 3, lk = lane & 7;
  float acc[4][4];
  #pragma unroll
  for (int a = 0; a < 4; a++)
    #pragma unroll
    for (int c = 0; c < 4; c++) acc[a][c] = 0.f;

  const float* qw = qs + wave * 64;
  for (int dq = 0; dq < 16; dq++) {
    float4 q4 = *(const float4*)(qw + dq * 4);     // broadcast
    const int cj = (((dq + lj) & 15) << 2);
    const int ck = (((dq + lk) & 15) << 2);
    float4 t4[4], kp4[4];
    #pragma unroll
    for (int tj = 0; tj < 4; tj++) {
      float4 kv = *(const float4*)(Kn + (lj * 4 + tj) * 64 + cj);
      t4[tj].x = q4.x * kv.x; t4[tj].y = q4.y * kv.y;
      t4[tj].z = q4.z * kv.z; t4[tj].w = q4.w * kv.w;
    }
    #pragma unroll
    for (int tk = 0; tk < 4; tk++)
      kp4[tk] = *(const float4*)(Kp + (lk * 4 + tk) * 64 + ck);
    #pragma unroll
    for (int tj = 0; tj < 4; tj++)
      #pragma unroll
      for (int tk = 0; tk < 4; tk++)
        acc[tj][tk] += t4[tj].x * kp4[tk].x + t4[tj].y * kp4[tk].y
                     + t4[tj].z * kp4[tk].z + t4[tj].w * kp4[tk].w;
  }

  float amax = -1e30f;
  #pragma unroll
  for (int tj = 0; tj < 4; tj++)
    #pragma unroll
    for (int tk = 0; tk < 4; tk++) {
      int j = lj * 4 + tj, k = lk * 4 + tk;
      if (j <= m && k <= m) amax = fmaxf(amax, acc[tj][tk] * 0.125f);
    }
  #pragma unroll
  for (int off = 1; off < 64; off <<= 1) amax = fmaxf(amax, __shfl_xor(amax, off));

  float lsum = 0.f;
  float* ptw = Pt + wave * 1152;
  #pragma unroll
  for (int tk = 0; tk < 4; tk++) {
    int k = lk * 4 + tk;
    float4 ev; float* e = (float*)&ev;
    #pragma unroll
    for (int tj = 0; tj < 4; tj++) {
      int j = lj * 4 + tj;
      float xv = 0.f;
      if (j <= m && k <= m) xv = __expf(acc[tj][tk] * 0.125f - amax);
      e[tj] = xv; lsum += xv;
    }
    *(float4*)(ptw + k * 36 + lj * 4) = ev;        // b128 write
  }
  #pragma unroll
  for (int off = 1; off < 64; off <<= 1) lsum += __shfl_xor(lsum, off);
  float inv = 1.f / lsum;
  __builtin_amdgcn_wave_barrier();

  float vreg[32];                    // V column from LDS (2-way, free)
  #pragma unroll
  for (int k = 0; k < 32; k++) vreg[k] = Vs[k * 64 + lane];
  float zacc = 0.f;
  for (int k = 0; k <= m; k++) {
    float g0 = 0.f, g1 = 0.f, g2 = 0.f, g3 = 0.f;
    #pragma unroll
    for (int jq = 0; jq < 8; jq++) {
      float4 p = *(const float4*)(ptw + k * 36 + jq * 4);  // b128 broadcast
      g0 = fmaf(p.x, vreg[jq * 4 + 0], g0);
      g1 = fmaf(p.y, vreg[jq * 4 + 1], g1);
      g2 = fmaf(p.z, vreg[jq * 4 + 2], g2);
      g3 = fmaf(p.w, vreg[jq * 4 + 3], g3);
    }
    zacc = fmaf((g0 + g1) + (g2 + g3), vreg[k], zacc);
  }
  Z[r * 1024 + h * 64 + lane] = zacc * inv;
}

// ---- P4: wo partial tile. pid 0..127 -> (col0, ks of 8x128k) --------------
__device__ __forceinline__ void wo_tile(
    int pid, int tid, const float* __restrict__ Zr,
    const float* __restrict__ Wo, float* __restrict__ ws, float* xs) {
  const int col0 = (pid & 15) * 64;
  const int ks   = pid >> 4;                 // 0..7
  const int k0   = ks * 128;
  #pragma unroll
  for (int i = 0; i < 8; i++) {
    int e = i * 256 + tid; int r = e >> 5, q = e & 31;
    float4 v = *(const float4*)(Zr + r * 1024 + k0 + q * 4);
    xs[(q * 4 + 0) * 65 + r] = v.x;
    xs[(q * 4 + 1) * 65 + r] = v.y;
    xs[(q * 4 + 2) * 65 + r] = v.z;
    xs[(q * 4 + 3) * 65 + r] = v.w;
  }
  __syncthreads();
  const int wave = __builtin_amdgcn_readfirstlane(tid >> 6);
  const int lane = tid & 63;
  const float* __restrict__ Wt = Wo + (size_t)k0 * 1024 + col0 + wave * 16;
  float acc[16];
  #pragma unroll
  for (int c = 0; c < 16; c++) acc[c] = 0.f;
  #pragma unroll 4
  for (int kk = 0; kk < 128; kk++) {
    float xv = xs[kk * 65 + lane];
    const float* __restrict__ wrow = Wt + kk * 1024;
    #pragma unroll
    for (int c = 0; c < 16; c++) acc[c] = fmaf(xv, wrow[c], acc[c]);
  }
  __syncthreads();
  #pragma unroll
  for (int c = 0; c < 16; c++) xs[lane * 65 + wave * 16 + c] = acc[c];
  __syncthreads();
  float* __restrict__ Do = ws + DPART_OFF + (size_t)ks * 65536 + col0;
  #pragma unroll
  for (int i = 0; i < 16; i++) {
    int r = wave * 16 + i;
    Do[r * 1024 + lane] = xs[r * 65 + lane];
  }
}

// ---- P2 helper ------------------------------------------------------------
__device__ __forceinline__ void reduce_chunk(int bid, int tid,
                                             float* __restrict__ ws) {
  int i = bid * 256 + tid;                   // 65536 float4 outputs
  const float4* __restrict__ p4 = (const float4*)(ws + YPART_OFF);
  float4 a = p4[i];
  #pragma unroll
  for (int s = 1; s < NS; s++) {
    float4 p = p4[(size_t)s * 65536 + i];
    a.x += p.x; a.y += p.y; a.z += p.z; a.w += p.w;
  }
  ((float4*)(ws + YFULL_OFF))[i] = a;
}

// ============================ fused cooperative ============================
__global__ __launch_bounds__(256, 4) void fused_kernel(
    const float* __restrict__ x,
    const float* __restrict__ Wq, const float* __restrict__ Wk,
    const float* __restrict__ Wkp, const float* __restrict__ Wv,
    const float* __restrict__ Wo,
    const float* __restrict__ gam, const float* __restrict__ bet,
    float* __restrict__ out, float* __restrict__ ws) {
  cg::grid_group grid = cg::this_grid();
  __shared__ float smem[SMEM_FLOATS];
  const int tid = threadIdx.x, bid = blockIdx.x;
  const int wave = tid >> 6, lane = tid & 63;
  const float4* x4 = (const float4*)x;
  const float4* g4 = (const float4*)gam;
  const float4* b4 = (const float4*)bet;
  float4* out4 = (float4*)out;

  // P1: proj partials (blocks 0..511) || LN bulk (blocks 512..1023)
  if (bid < 512) {
    proj_tile(bid, tid, x, Wq, Wk, Wkp, Wv, ws, smem);
  } else {
    int base = (bid - 512) * 8 + wave * 2;
    #pragma unroll
    for (int i = 0; i < 2; i++) {
      int rid = base + i;
      if (rid < 4032) {
        int b = rid >= 2016 ? 1 : 0;
        int s = rid - b * 2016;
        ln_row<false>(b * 2048 + s, 0, lane, x4, nullptr, g4, b4, out4);
      }
    }
  }
  grid.sync();

  // P2: reduce 8 Y partials -> Yfull
  if (bid < 256) reduce_chunk(bid, tid, ws);
  grid.sync();

  // P3: attention
  if (bid < 512) attn_block(bid, tid, ws + YFULL_OFF, ws + ZOFF, smem);
  grid.sync();

  // P4: wo partials
  if (bid < 128) wo_tile(bid, tid, ws + ZOFF, Wo, ws, smem);
  grid.sync();

  // P5: LN window rows (+ sum 8 delta partials)
  if (bid < 16) {
    int rid = bid * 4 + wave;        // 0..63
    int b = rid >> 5, sl = rid & 31;
    ln_row<true>(b * 2048 + 2016 + sl, rid, lane, x4,
                 (const float4*)(ws + DPART_OFF), g4, b4, out4);
  }
}

// ============================ fallback kernels =============================
__global__ __launch_bounds__(256, 4) void k_p1(
    const float* __restrict__ x,
    const float* __restrict__ Wq, const float* __restrict__ Wk,
    const float* __restrict__ Wkp, const float* __restrict__ Wv,
    const float* __restrict__ gam, const float* __restrict__ bet,
    float* __restrict__ out, float* __restrict__ ws) {
  __shared__ float smem[SMEM_FLOATS];
  const int tid = threadIdx.x, bid = blockIdx.x;
  const int wave = tid >> 6, lane = tid & 63;
  if (bid < 512) {
    proj_tile(bid, tid, x, Wq, Wk, Wkp, Wv, ws, smem);
  } else {
    int base = (bid - 512) * 8 + wave * 2;
    #pragma unroll
    for (int i = 0; i < 2; i++) {
      int rid = base + i;
      if (rid < 4032) {
        int b = rid >= 2016 ? 1 : 0;
        int s = rid - b * 2016;
        ln_row<false>(b * 2048 + s, 0, lane, (const float4*)x, nullptr,
                      (const float4*)gam, (const float4*)bet, (float4*)out);
      }
    }
  }
}

__global__ __launch_bounds__(256, 4) void k_p2(float* __restrict__ ws) {
  reduce_chunk(blockIdx.x, threadIdx.x, ws);
}

__global__ __launch_bounds__(256, 4) void k_p3(float* __restrict__ ws) {
  __shared__ float smem[SMEM_FLOATS];
  attn_block(blockIdx.x, threadIdx.x, ws + YFULL_OFF, ws + ZOFF, smem);
}

__global__ __launch_bounds__(256, 4) void k_p4(const float* __restrict__ Wo,
                                               float* __restrict__ ws) {
  __shared__ float smem[SMEM_FLOATS];
  wo_tile(blockIdx.x, threadIdx.x, ws + ZOFF, Wo, ws, smem);
}

__global__ __launch_bounds__(256, 4) void k_p5(
    const float* __restrict__ x, const float* __restrict__ gam,
    const float* __restrict__ bet, float* __restrict__ out,
    float* __restrict__ ws) {
  int rid = blockIdx.x * 4 + (threadIdx.x >> 6);
  int b = rid >> 5, sl = rid & 31;
  ln_row<true>(b * 2048 + 2016 + sl, rid, threadIdx.x & 63, (const float4*)x,
               (const float4*)(ws + DPART_OFF), (const float4*)gam,
               (const float4*)bet, (float4*)out);
}

// ---------------------------------------------------------------------------
extern "C" void kernel_launch(void* const* d_in, const int* in_sizes, int n_in,
                              void* d_out, int out_size, void* d_ws, size_t ws_size,
                              hipStream_t stream) {
  const float* x   = (const float*)d_in[0];
  const float* Wq  = (const float*)d_in[1];
  const float* Wk  = (const float*)d_in[2];
  const float* Wv  = (const float*)d_in[3];  // dict order: W_V before W_Kp
  const float* Wkp = (const float*)d_in[4];
  const float* Wo  = (const float*)d_in[5];
  const float* gam = (const float*)d_in[6];
  const float* bet = (const float*)d_in[7];
  float* out = (float*)d_out;
  float* ws  = (float*)d_ws;   // needs ~11.8 MB

  void* args[] = { (void*)&x, (void*)&Wq, (void*)&Wk, (void*)&Wkp, (void*)&Wv,
                   (void*)&Wo, (void*)&gam, (void*)&bet, (void*)&out, (void*)&ws };
  hipError_t err = hipLaunchCooperativeKernel(
      (const void*)fused_kernel, dim3(1024), dim3(256), args, 0, stream);
  if (err != hipSuccess) {
    // fallback: same phases as separate kernels
    hipLaunchKernelGGL(k_p1, dim3(1024), dim3(256), 0, stream,
                       x, Wq, Wk, Wkp, Wv, gam, bet, out, ws);
    hipLaunchKernelGGL(k_p2, dim3(256), dim3(256), 0, stream, ws);
    hipLaunchKernelGGL(k_p3, dim3(512), dim3(256), 0, stream, ws);
    hipLaunchKernelGGL(k_p4, dim3(128), dim3(256), 0, stream, Wo, ws);
    hipLaunchKernelGGL(k_p5, dim3(16), dim3(256), 0, stream,
                       x, gam, bet, out, ws);
  }
}